// Round 3
// baseline (485.615 us; speedup 1.0000x reference)
//
#include <hip/hip_runtime.h>
#include <math.h>

#define VIF_EPS       1e-10f
#define SIGMA_NSQ     2.0f
#define SIGMA_MAX_INV (4.0f / (255.0f * 255.0f))
#define GAIN_LIMIT    100.0f

// jnp.pad mode='reflect' (no edge duplication). Overshoot < dim, single reflection suffices.
__device__ __forceinline__ int reflect_idx(int i, int n) {
    i = (i < 0) ? -i : i;
    i = (i >= n) ? (2 * n - 2 - i) : i;
    return i;
}

// Reference: sigma=N/5; g=exp(-x^2/(2 sigma^2)); win=outer(g,g)/sum -> separable gn = g/sum(g).
template <int N>
__device__ __forceinline__ void compute_weights(float* wts) {
    if (threadIdx.x == 0) {
        const float sigma = (float)N / 5.0f;
        const float denom = 2.0f * sigma * sigma;
        float s = 0.0f;
        for (int i = 0; i < N; ++i) {
            float x = (float)i - (float)(N - 1) * 0.5f;
            float g = expf(-(x * x) / denom);
            wts[i] = g;
            s += g;
        }
        for (int i = 0; i < N; ++i) wts[i] = wts[i] / s;
    }
}

// Host-side mirror of the tile width choice.
constexpr int tile_w(int N) { return (128 - (N - 1)) & ~3; }

// Vertical-first separable VIF stats.
// Phase 1: 256 threads = 128 columns x 2 row-groups; each thread loads its column's
//   rows from GLOBAL (coalesced), forms the 5 product channels in registers, and does
//   the N-tap vertical conv in registers (4 outputs/thread). Only the vertical results
//   go to LDS: v[5][8][132] (stride 132 -> 4-bank rotation per row).
// Phase 2: threads take 4 consecutive x-outputs each, float4 register windows from v,
//   N-tap horizontal conv + VIF per-pixel math, block reduction -> double2 partial.
template <int N>
__global__ __launch_bounds__(256, 5) void stats_kernel(
    const float* __restrict__ refp, const float* __restrict__ distp,
    int h, int w, float shift, double2* __restrict__ partial) {
    constexpr int P   = (N - 1) / 2;
    constexpr int VC  = 128;              // columns incl. halo
    constexpr int TW  = tile_w(N);        // output columns per block
    constexpr int TH  = 8;                // output rows per block
    constexpr int Q   = 4;                // rows per thread (phase 1)
    constexpr int LR  = Q + 2 * P;        // rows loaded per thread
    constexpr int VCP = VC + 4;           // padded LDS row stride (132)
    constexpr int XG  = TW / 4;           // x-groups (phase 2)
    constexpr int F4  = (N + 6) / 4;      // float4s covering N+3 floats

    __shared__ float wts[N];
    __shared__ __align__(16) float v[5][TH][VCP];
    __shared__ float rsum[8];

    const int tid = threadIdx.x;
    const int b   = blockIdx.z;
    const int x0  = blockIdx.x * TW;
    const int y0  = blockIdx.y * TH;

    compute_weights<N>(wts);
    __syncthreads();

    // Weights to registers: no LDS broadcasts in the hot loops.
    float wr[N];
#pragma unroll
    for (int j = 0; j < N; ++j) wr[j] = wts[j];

    // ---- Phase 1: vertical conv from global ----
    {
        const int c = tid & (VC - 1);
        const int g = tid >> 7;           // 0..1
        const int gx = reflect_idx(x0 + c - P, w);
        const float* rb = refp  + (size_t)b * h * w + gx;
        const float* db = distp + (size_t)b * h * w + gx;

        float acc[5][Q];
#pragma unroll
        for (int ch = 0; ch < 5; ++ch)
#pragma unroll
            for (int q = 0; q < Q; ++q) acc[ch][q] = 0.f;

#pragma unroll
        for (int i = 0; i < LR; ++i) {
            int gy = reflect_idx(y0 + g * Q - P + i, h);
            float r = rb[(size_t)gy * w] - shift;
            float d = db[(size_t)gy * w] - shift;
            float p0 = r, p1 = d, p2 = r * r, p3 = d * d, p4 = r * d;
#pragma unroll
            for (int q = 0; q < Q; ++q) {
                int j = i - q;
                if (j >= 0 && j < N) {
                    float wj = wr[j];
                    acc[0][q] += wj * p0;
                    acc[1][q] += wj * p1;
                    acc[2][q] += wj * p2;
                    acc[3][q] += wj * p3;
                    acc[4][q] += wj * p4;
                }
            }
        }
#pragma unroll
        for (int ch = 0; ch < 5; ++ch)
#pragma unroll
            for (int q = 0; q < Q; ++q)
                v[ch][g * Q + q][c] = acc[ch][q];
    }
    __syncthreads();

    // ---- Phase 2: horizontal conv + VIF math ----
    float num_v = 0.f, den_v = 0.f;
    {
        const int xg  = tid & 31;
        const int row = tid >> 5;         // 0..7
        if (xg < XG) {
            float mu[5][4];
#pragma unroll
            for (int ch = 0; ch < 5; ++ch) {
                float win[F4 * 4];
                const float4* s4 = (const float4*)&v[ch][row][xg * 4];
#pragma unroll
                for (int f = 0; f < F4; ++f) {
                    float4 t = s4[f];
                    win[4 * f + 0] = t.x; win[4 * f + 1] = t.y;
                    win[4 * f + 2] = t.z; win[4 * f + 3] = t.w;
                }
#pragma unroll
                for (int q = 0; q < 4; ++q) {
                    float a = 0.f;
#pragma unroll
                    for (int j = 0; j < N; ++j) a += wr[j] * win[q + j];
                    mu[ch][q] = a;
                }
            }
            const int gy = y0 + row;
#pragma unroll
            for (int q = 0; q < 4; ++q) {
                int gx = x0 + xg * 4 + q;
                if (gx < w && gy < h) {
                    float mu1 = mu[0][q], mu2 = mu[1][q];
                    float s1  = fmaxf(0.f, mu[2][q] - mu1 * mu1);
                    float s2  = fmaxf(0.f, mu[3][q] - mu2 * mu2);
                    float s12 = mu[4][q] - mu1 * mu2;

                    float g  = s12 / (s1 + VIF_EPS);
                    float sv = s2 - g * s12;
                    if (s1 < VIF_EPS) { g = 0.f; sv = s2; s1 = 0.f; }
                    if (s2 < VIF_EPS) { g = 0.f; sv = 0.f; }
                    if (g  < 0.f)     { sv = s2; g = 0.f; }
                    if (sv <= VIF_EPS) sv = VIF_EPS;
                    g = fminf(g, GAIN_LIMIT);

                    float num_ar = __log2f(1.f + g * g * s1 / (sv + SIGMA_NSQ));
                    float den_ar = __log2f(1.f + s1 / SIGMA_NSQ);
                    if (s12 < 0.f) num_ar = 0.f;
                    if (s1 < SIGMA_NSQ) { num_ar = 1.f - s2 * SIGMA_MAX_INV; den_ar = 1.f; }
                    num_v += num_ar;
                    den_v += den_ar;
                }
            }
        }
    }

    // Block reduction: wave shuffle then cross-wave via LDS.
#pragma unroll
    for (int off = 32; off > 0; off >>= 1) {
        num_v += __shfl_down(num_v, off);
        den_v += __shfl_down(den_v, off);
    }
    const int wid = tid >> 6, lane = tid & 63;
    if (lane == 0) { rsum[wid] = num_v; rsum[4 + wid] = den_v; }
    __syncthreads();
    if (tid == 0) {
        float ns = rsum[0] + rsum[1] + rsum[2] + rsum[3];
        float ds = rsum[4] + rsum[5] + rsum[6] + rsum[7];
        size_t pidx = ((size_t)b * gridDim.y + blockIdx.y) * gridDim.x + blockIdx.x;
        partial[pidx] = make_double2((double)ns, (double)ds);
    }
}

// Separable stride-2 Gaussian downsample, LDS-tiled, both images per block.
template <int N>
__global__ __launch_bounds__(256) void down_kernel(
    const float* __restrict__ rin, const float* __restrict__ din,
    float* __restrict__ rout, float* __restrict__ dout,
    int h, int w, int h2, int w2, float shift) {
    constexpr int P   = (N - 1) / 2;
    constexpr int TOX = 32, TOY = 8;
    constexpr int IH  = 2 * (TOY - 1) + N;
    constexpr int IW  = 2 * (TOX - 1) + N;
    constexpr int IWP = ((IW + 3) / 4) * 4;
    constexpr int F4  = (N + 10) / 4;
    constexpr int NG  = 2 * IH * (TOX / 4);

    __shared__ float wts[N];
    __shared__ __align__(16) float lin[2 * IH * IWP];
    __shared__ float hd[2][IH][TOX];

    compute_weights<N>(wts);

    const int tid = threadIdx.x;
    const int b   = blockIdx.z;
    const int x0  = blockIdx.x * TOX;
    const int y0  = blockIdx.y * TOY;

    const float* src0 = rin + (size_t)b * h * w;
    const float* src1 = din + (size_t)b * h * w;

    for (int idx = tid; idx < 2 * IH * IWP; idx += 256) {
        int img = idx / (IH * IWP);
        int rem = idx - img * IH * IWP;
        int r   = rem / IWP;
        int cx  = rem - r * IWP;
        int gy  = reflect_idx(2 * y0 - P + r, h);
        int gx  = reflect_idx(2 * x0 - P + cx, w);
        const float* src = img ? src1 : src0;
        lin[idx] = src[(size_t)gy * w + gx] - shift;
    }
    __syncthreads();

    for (int g = tid; g < NG; g += 256) {
        int img = g / (IH * 8);
        int rem = g - img * IH * 8;
        int r   = rem >> 3;
        int xg  = (rem & 7) * 4;
        float win[F4 * 4];
        const float4* src4 = (const float4*)&lin[(img * IH + r) * IWP + 2 * xg];
#pragma unroll
        for (int f = 0; f < F4; ++f) {
            float4 v = src4[f];
            win[4 * f + 0] = v.x; win[4 * f + 1] = v.y;
            win[4 * f + 2] = v.z; win[4 * f + 3] = v.w;
        }
#pragma unroll
        for (int q = 0; q < 4; ++q) {
            float a = 0.f;
#pragma unroll
            for (int j = 0; j < N; ++j) a += wts[j] * win[2 * q + j];
            hd[img][r][xg + q] = a;
        }
    }
    __syncthreads();

    const int img = tid >> 7;
    const int rem = tid & 127;
    const int tx  = rem & 31;
    const int yg  = (rem >> 5) * 2;
    float* outp = (img ? dout : rout) + (size_t)b * h2 * w2;
#pragma unroll
    for (int q = 0; q < 2; ++q) {
        int yo = yg + q;
        int gy = y0 + yo, gx = x0 + tx;
        if (gy < h2 && gx < w2) {
            float a = 0.f;
#pragma unroll
            for (int j = 0; j < N; ++j) a += wts[j] * hd[img][2 * yo + j][tx];
            outp[(size_t)gy * w2 + gx] = a;
        }
    }
}

// 16 blocks: one per (batch, scale). Sums double2 partials, writes num/den to out.
__global__ __launch_bounds__(256) void reduce_kernel(
    const double2* __restrict__ part, float* __restrict__ out,
    int4 bases, int4 counts) {
    __shared__ double sn[4], sd[4];
    const int s = blockIdx.x & 3;
    const int b = blockIdx.x >> 2;
    const int base = (&bases.x)[s];
    const int cnt  = (&counts.x)[s];
    const double2* p = part + base + (size_t)b * cnt;

    double ns = 0.0, ds = 0.0;
    for (int i = threadIdx.x; i < cnt; i += 256) {
        double2 v = p[i];
        ns += v.x;
        ds += v.y;
    }
#pragma unroll
    for (int off = 32; off > 0; off >>= 1) {
        ns += __shfl_down(ns, off);
        ds += __shfl_down(ds, off);
    }
    const int wid = threadIdx.x >> 6, lane = threadIdx.x & 63;
    if (lane == 0) { sn[wid] = ns; sd[wid] = ds; }
    __syncthreads();
    if (threadIdx.x == 0) {
        double Nv = sn[0] + sn[1] + sn[2] + sn[3];
        double Dv = sd[0] + sd[1] + sd[2] + sd[3];
        out[b * 4 + s] = (float)(Nv / Dv);
    }
}

extern "C" void kernel_launch(void* const* d_in, const int* in_sizes, int n_in,
                              void* d_out, int out_size, void* d_ws, size_t ws_size,
                              hipStream_t stream) {
    const float* ref  = (const float*)d_in[0];
    const float* dist = (const float*)d_in[1];
    float* out = (float*)d_out;

    const int B = 4;
    const int H0 = 1080, W0 = 1920;
    const int H1 = 540,  W1 = 960;
    const int H2 = 270,  W2 = 480;
    const int H3 = 135,  W3 = 240;

    char*  ws  = (char*)d_ws;
    size_t off = 0;
    auto alloc = [&](size_t bytes) -> void* {
        void* p = ws + off;
        off += (bytes + 255) & ~(size_t)255;
        return p;
    };
    float* ref1  = (float*)alloc((size_t)B * H1 * W1 * 4);
    float* dist1 = (float*)alloc((size_t)B * H1 * W1 * 4);
    float* ref2  = (float*)alloc((size_t)B * H2 * W2 * 4);
    float* dist2 = (float*)alloc((size_t)B * H2 * W2 * 4);
    float* ref3  = (float*)alloc((size_t)B * H3 * W3 * 4);
    float* dist3 = (float*)alloc((size_t)B * H3 * W3 * 4);

    // Stats grids (tile = tile_w(N) x 8)
    const int tx0 = (W0 + tile_w(17) - 1) / tile_w(17), ty0 = (H0 + 7) / 8;  // 18 x 135
    const int tx1 = (W1 + tile_w(9)  - 1) / tile_w(9),  ty1 = (H1 + 7) / 8;  // 8 x 68
    const int tx2 = (W2 + tile_w(5)  - 1) / tile_w(5),  ty2 = (H2 + 7) / 8;  // 4 x 34
    const int tx3 = (W3 + tile_w(3)  - 1) / tile_w(3),  ty3 = (H3 + 7) / 8;  // 2 x 17
    const int n0 = tx0 * ty0, n1 = tx1 * ty1, n2 = tx2 * ty2, n3 = tx3 * ty3;

    double2* part = (double2*)alloc((size_t)B * (n0 + n1 + n2 + n3) * sizeof(double2));
    double2* p0 = part;
    double2* p1 = p0 + (size_t)B * n0;
    double2* p2 = p1 + (size_t)B * n1;
    double2* p3 = p2 + (size_t)B * n2;

    dim3 blk(256);

    // Scale 0: stats on original (shift 128)
    stats_kernel<17><<<dim3(tx0, ty0, B), blk, 0, stream>>>(ref, dist, H0, W0, 128.0f, p0);

    // Scale 1
    down_kernel<9><<<dim3((W1 + 31) / 32, (H1 + 7) / 8, B), blk, 0, stream>>>(
        ref, dist, ref1, dist1, H0, W0, H1, W1, 128.0f);
    stats_kernel<9><<<dim3(tx1, ty1, B), blk, 0, stream>>>(ref1, dist1, H1, W1, 0.0f, p1);

    // Scale 2
    down_kernel<5><<<dim3((W2 + 31) / 32, (H2 + 7) / 8, B), blk, 0, stream>>>(
        ref1, dist1, ref2, dist2, H1, W1, H2, W2, 0.0f);
    stats_kernel<5><<<dim3(tx2, ty2, B), blk, 0, stream>>>(ref2, dist2, H2, W2, 0.0f, p2);

    // Scale 3
    down_kernel<3><<<dim3((W3 + 31) / 32, (H3 + 7) / 8, B), blk, 0, stream>>>(
        ref2, dist2, ref3, dist3, H2, W2, H3, W3, 0.0f);
    stats_kernel<3><<<dim3(tx3, ty3, B), blk, 0, stream>>>(ref3, dist3, H3, W3, 0.0f, p3);

    // Final: num/den per (b, scale)
    reduce_kernel<<<16, 256, 0, stream>>>(
        part, out,
        make_int4(0, B * n0, B * (n0 + n1), B * (n0 + n1 + n2)),
        make_int4(n0, n1, n2, n3));
}

// Round 4
// 241.304 us; speedup vs baseline: 2.0125x; 2.0125x over previous
//
#include <hip/hip_runtime.h>
#include <math.h>

#define VIF_EPS       1e-10f
#define SIGMA_NSQ     2.0f
#define SIGMA_MAX_INV (4.0f / (255.0f * 255.0f))
#define GAIN_LIMIT    100.0f

// jnp.pad mode='reflect' (no edge duplication). Overshoot < dim, single reflection suffices.
__device__ __forceinline__ int reflect_idx(int i, int n) {
    i = (i < 0) ? -i : i;
    i = (i >= n) ? (2 * n - 2 - i) : i;
    return i;
}

// Reference: sigma=N/5; g=exp(-x^2/(2 sigma^2)); win=outer(g,g)/sum -> separable gn = g/sum(g).
template <int N>
__device__ __forceinline__ void compute_weights(float* wts) {
    if (threadIdx.x == 0) {
        const float sigma = (float)N / 5.0f;
        const float denom = 2.0f * sigma * sigma;
        float s = 0.0f;
        for (int i = 0; i < N; ++i) {
            float x = (float)i - (float)(N - 1) * 0.5f;
            float g = expf(-(x * x) / denom);
            wts[i] = g;
            s += g;
        }
        for (int i = 0; i < N; ++i) wts[i] = wts[i] / s;
    }
}

// Host-side mirror of the tile width choice.
constexpr int tile_w(int N) { return (128 - (N - 1)) & ~3; }

// Vertical-first separable VIF stats. Grid is Y-MAJOR (blockIdx.x = row tile) so
// vertical-halo re-reads hit L2/L3 from temporally-adjacent blocks.
// Phase 1: 256 threads = 128 columns x 2 row-groups; coalesced global column loads,
//   5 product channels + N-tap vertical conv entirely in registers (4 outputs/thread).
//   Only vertical results go to LDS: v[5][8][132] (stride 132 -> 4-bank rotation/row).
// Phase 2: 4 consecutive x-outputs/thread, float4 register windows from v,
//   N-tap horizontal conv + VIF per-pixel math, block reduction -> double2 partial.
// NOTE: plain __launch_bounds__(256) — round 3's (256,5) forced VGPR=48 and spilled
// ~930 MB/dispatch of scratch traffic.
template <int N>
__global__ __launch_bounds__(256) void stats_kernel(
    const float* __restrict__ refp, const float* __restrict__ distp,
    int h, int w, float shift, double2* __restrict__ partial) {
    constexpr int P   = (N - 1) / 2;
    constexpr int VC  = 128;              // columns incl. halo
    constexpr int TW  = tile_w(N);        // output columns per block
    constexpr int TH  = 8;                // output rows per block
    constexpr int Q   = 4;                // rows per thread (phase 1)
    constexpr int LR  = Q + 2 * P;        // rows loaded per thread
    constexpr int VCP = VC + 4;           // padded LDS row stride (132)
    constexpr int XG  = TW / 4;           // x-groups (phase 2)
    constexpr int F4  = (N + 6) / 4;      // float4s covering N+3 floats

    __shared__ float wts[N];
    __shared__ __align__(16) float v[5][TH][VCP];
    __shared__ float rsum[8];

    const int tid = threadIdx.x;
    const int b   = blockIdx.z;
    const int x0  = blockIdx.y * TW;      // y-major: blockIdx.y is the x tile
    const int y0  = blockIdx.x * TH;      //          blockIdx.x is the y tile

    compute_weights<N>(wts);
    __syncthreads();

    // Weights to registers: no LDS broadcasts in the hot loops.
    float wr[N];
#pragma unroll
    for (int j = 0; j < N; ++j) wr[j] = wts[j];

    // ---- Phase 1: vertical conv from global ----
    {
        const int c = tid & (VC - 1);
        const int g = tid >> 7;           // 0..1
        const int gx = reflect_idx(x0 + c - P, w);
        const float* rb = refp  + (size_t)b * h * w + gx;
        const float* db = distp + (size_t)b * h * w + gx;

        float acc[5][Q];
#pragma unroll
        for (int ch = 0; ch < 5; ++ch)
#pragma unroll
            for (int q = 0; q < Q; ++q) acc[ch][q] = 0.f;

#pragma unroll
        for (int i = 0; i < LR; ++i) {
            int gy = reflect_idx(y0 + g * Q - P + i, h);
            float r = rb[(size_t)gy * w] - shift;
            float d = db[(size_t)gy * w] - shift;
            float p0 = r, p1 = d, p2 = r * r, p3 = d * d, p4 = r * d;
#pragma unroll
            for (int q = 0; q < Q; ++q) {
                int j = i - q;
                if (j >= 0 && j < N) {
                    float wj = wr[j];
                    acc[0][q] += wj * p0;
                    acc[1][q] += wj * p1;
                    acc[2][q] += wj * p2;
                    acc[3][q] += wj * p3;
                    acc[4][q] += wj * p4;
                }
            }
        }
#pragma unroll
        for (int ch = 0; ch < 5; ++ch)
#pragma unroll
            for (int q = 0; q < Q; ++q)
                v[ch][g * Q + q][c] = acc[ch][q];
    }
    __syncthreads();

    // ---- Phase 2: horizontal conv + VIF math ----
    float num_v = 0.f, den_v = 0.f;
    {
        const int xg  = tid & 31;
        const int row = tid >> 5;         // 0..7
        if (xg < XG) {
            float mu[5][4];
#pragma unroll
            for (int ch = 0; ch < 5; ++ch) {
                float win[F4 * 4];
                const float4* s4 = (const float4*)&v[ch][row][xg * 4];
#pragma unroll
                for (int f = 0; f < F4; ++f) {
                    float4 t = s4[f];
                    win[4 * f + 0] = t.x; win[4 * f + 1] = t.y;
                    win[4 * f + 2] = t.z; win[4 * f + 3] = t.w;
                }
#pragma unroll
                for (int q = 0; q < 4; ++q) {
                    float a = 0.f;
#pragma unroll
                    for (int j = 0; j < N; ++j) a += wr[j] * win[q + j];
                    mu[ch][q] = a;
                }
            }
            const int gy = y0 + row;
#pragma unroll
            for (int q = 0; q < 4; ++q) {
                int gx = x0 + xg * 4 + q;
                if (gx < w && gy < h) {
                    float mu1 = mu[0][q], mu2 = mu[1][q];
                    float s1  = fmaxf(0.f, mu[2][q] - mu1 * mu1);
                    float s2  = fmaxf(0.f, mu[3][q] - mu2 * mu2);
                    float s12 = mu[4][q] - mu1 * mu2;

                    float g  = s12 / (s1 + VIF_EPS);
                    float sv = s2 - g * s12;
                    if (s1 < VIF_EPS) { g = 0.f; sv = s2; s1 = 0.f; }
                    if (s2 < VIF_EPS) { g = 0.f; sv = 0.f; }
                    if (g  < 0.f)     { sv = s2; g = 0.f; }
                    if (sv <= VIF_EPS) sv = VIF_EPS;
                    g = fminf(g, GAIN_LIMIT);

                    float num_ar = __log2f(1.f + g * g * s1 / (sv + SIGMA_NSQ));
                    float den_ar = __log2f(1.f + s1 / SIGMA_NSQ);
                    if (s12 < 0.f) num_ar = 0.f;
                    if (s1 < SIGMA_NSQ) { num_ar = 1.f - s2 * SIGMA_MAX_INV; den_ar = 1.f; }
                    num_v += num_ar;
                    den_v += den_ar;
                }
            }
        }
    }

    // Block reduction: wave shuffle then cross-wave via LDS.
#pragma unroll
    for (int off = 32; off > 0; off >>= 1) {
        num_v += __shfl_down(num_v, off);
        den_v += __shfl_down(den_v, off);
    }
    const int wid = tid >> 6, lane = tid & 63;
    if (lane == 0) { rsum[wid] = num_v; rsum[4 + wid] = den_v; }
    __syncthreads();
    if (tid == 0) {
        float ns = rsum[0] + rsum[1] + rsum[2] + rsum[3];
        float ds = rsum[4] + rsum[5] + rsum[6] + rsum[7];
        size_t pidx = ((size_t)b * gridDim.x + blockIdx.x) * gridDim.y + blockIdx.y;
        partial[pidx] = make_double2((double)ns, (double)ds);
    }
}

// Separable stride-2 Gaussian downsample, LDS-tiled, both images per block.
template <int N>
__global__ __launch_bounds__(256) void down_kernel(
    const float* __restrict__ rin, const float* __restrict__ din,
    float* __restrict__ rout, float* __restrict__ dout,
    int h, int w, int h2, int w2, float shift) {
    constexpr int P   = (N - 1) / 2;
    constexpr int TOX = 32, TOY = 8;
    constexpr int IH  = 2 * (TOY - 1) + N;
    constexpr int IW  = 2 * (TOX - 1) + N;
    constexpr int IWP = ((IW + 3) / 4) * 4;
    constexpr int F4  = (N + 10) / 4;
    constexpr int NG  = 2 * IH * (TOX / 4);

    __shared__ float wts[N];
    __shared__ __align__(16) float lin[2 * IH * IWP];
    __shared__ float hd[2][IH][TOX];

    compute_weights<N>(wts);

    const int tid = threadIdx.x;
    const int b   = blockIdx.z;
    const int x0  = blockIdx.x * TOX;
    const int y0  = blockIdx.y * TOY;

    const float* src0 = rin + (size_t)b * h * w;
    const float* src1 = din + (size_t)b * h * w;

    for (int idx = tid; idx < 2 * IH * IWP; idx += 256) {
        int img = idx / (IH * IWP);
        int rem = idx - img * IH * IWP;
        int r   = rem / IWP;
        int cx  = rem - r * IWP;
        int gy  = reflect_idx(2 * y0 - P + r, h);
        int gx  = reflect_idx(2 * x0 - P + cx, w);
        const float* src = img ? src1 : src0;
        lin[idx] = src[(size_t)gy * w + gx] - shift;
    }
    __syncthreads();

    for (int g = tid; g < NG; g += 256) {
        int img = g / (IH * 8);
        int rem = g - img * IH * 8;
        int r   = rem >> 3;
        int xg  = (rem & 7) * 4;
        float win[F4 * 4];
        const float4* src4 = (const float4*)&lin[(img * IH + r) * IWP + 2 * xg];
#pragma unroll
        for (int f = 0; f < F4; ++f) {
            float4 v = src4[f];
            win[4 * f + 0] = v.x; win[4 * f + 1] = v.y;
            win[4 * f + 2] = v.z; win[4 * f + 3] = v.w;
        }
#pragma unroll
        for (int q = 0; q < 4; ++q) {
            float a = 0.f;
#pragma unroll
            for (int j = 0; j < N; ++j) a += wts[j] * win[2 * q + j];
            hd[img][r][xg + q] = a;
        }
    }
    __syncthreads();

    const int img = tid >> 7;
    const int rem = tid & 127;
    const int tx  = rem & 31;
    const int yg  = (rem >> 5) * 2;
    float* outp = (img ? dout : rout) + (size_t)b * h2 * w2;
#pragma unroll
    for (int q = 0; q < 2; ++q) {
        int yo = yg + q;
        int gy = y0 + yo, gx = x0 + tx;
        if (gy < h2 && gx < w2) {
            float a = 0.f;
#pragma unroll
            for (int j = 0; j < N; ++j) a += wts[j] * hd[img][2 * yo + j][tx];
            outp[(size_t)gy * w2 + gx] = a;
        }
    }
}

// 16 blocks: one per (batch, scale). Sums double2 partials, writes num/den to out.
__global__ __launch_bounds__(256) void reduce_kernel(
    const double2* __restrict__ part, float* __restrict__ out,
    int4 bases, int4 counts) {
    __shared__ double sn[4], sd[4];
    const int s = blockIdx.x & 3;
    const int b = blockIdx.x >> 2;
    const int base = (&bases.x)[s];
    const int cnt  = (&counts.x)[s];
    const double2* p = part + base + (size_t)b * cnt;

    double ns = 0.0, ds = 0.0;
    for (int i = threadIdx.x; i < cnt; i += 256) {
        double2 v = p[i];
        ns += v.x;
        ds += v.y;
    }
#pragma unroll
    for (int off = 32; off > 0; off >>= 1) {
        ns += __shfl_down(ns, off);
        ds += __shfl_down(ds, off);
    }
    const int wid = threadIdx.x >> 6, lane = threadIdx.x & 63;
    if (lane == 0) { sn[wid] = ns; sd[wid] = ds; }
    __syncthreads();
    if (threadIdx.x == 0) {
        double Nv = sn[0] + sn[1] + sn[2] + sn[3];
        double Dv = sd[0] + sd[1] + sd[2] + sd[3];
        out[b * 4 + s] = (float)(Nv / Dv);
    }
}

extern "C" void kernel_launch(void* const* d_in, const int* in_sizes, int n_in,
                              void* d_out, int out_size, void* d_ws, size_t ws_size,
                              hipStream_t stream) {
    const float* ref  = (const float*)d_in[0];
    const float* dist = (const float*)d_in[1];
    float* out = (float*)d_out;

    const int B = 4;
    const int H0 = 1080, W0 = 1920;
    const int H1 = 540,  W1 = 960;
    const int H2 = 270,  W2 = 480;
    const int H3 = 135,  W3 = 240;

    char*  ws  = (char*)d_ws;
    size_t off = 0;
    auto alloc = [&](size_t bytes) -> void* {
        void* p = ws + off;
        off += (bytes + 255) & ~(size_t)255;
        return p;
    };
    float* ref1  = (float*)alloc((size_t)B * H1 * W1 * 4);
    float* dist1 = (float*)alloc((size_t)B * H1 * W1 * 4);
    float* ref2  = (float*)alloc((size_t)B * H2 * W2 * 4);
    float* dist2 = (float*)alloc((size_t)B * H2 * W2 * 4);
    float* ref3  = (float*)alloc((size_t)B * H3 * W3 * 4);
    float* dist3 = (float*)alloc((size_t)B * H3 * W3 * 4);

    // Stats grids (tile = tile_w(N) x 8), y-major: grid.x = row tiles, grid.y = col tiles.
    const int tx0 = (W0 + tile_w(17) - 1) / tile_w(17), ty0 = (H0 + 7) / 8;  // 18 x 135
    const int tx1 = (W1 + tile_w(9)  - 1) / tile_w(9),  ty1 = (H1 + 7) / 8;  // 8 x 68
    const int tx2 = (W2 + tile_w(5)  - 1) / tile_w(5),  ty2 = (H2 + 7) / 8;  // 4 x 34
    const int tx3 = (W3 + tile_w(3)  - 1) / tile_w(3),  ty3 = (H3 + 7) / 8;  // 2 x 17
    const int n0 = tx0 * ty0, n1 = tx1 * ty1, n2 = tx2 * ty2, n3 = tx3 * ty3;

    double2* part = (double2*)alloc((size_t)B * (n0 + n1 + n2 + n3) * sizeof(double2));
    double2* p0 = part;
    double2* p1 = p0 + (size_t)B * n0;
    double2* p2 = p1 + (size_t)B * n1;
    double2* p3 = p2 + (size_t)B * n2;

    dim3 blk(256);

    // Scale 0: stats on original (shift 128)
    stats_kernel<17><<<dim3(ty0, tx0, B), blk, 0, stream>>>(ref, dist, H0, W0, 128.0f, p0);

    // Scale 1
    down_kernel<9><<<dim3((W1 + 31) / 32, (H1 + 7) / 8, B), blk, 0, stream>>>(
        ref, dist, ref1, dist1, H0, W0, H1, W1, 128.0f);
    stats_kernel<9><<<dim3(ty1, tx1, B), blk, 0, stream>>>(ref1, dist1, H1, W1, 0.0f, p1);

    // Scale 2
    down_kernel<5><<<dim3((W2 + 31) / 32, (H2 + 7) / 8, B), blk, 0, stream>>>(
        ref1, dist1, ref2, dist2, H1, W1, H2, W2, 0.0f);
    stats_kernel<5><<<dim3(ty2, tx2, B), blk, 0, stream>>>(ref2, dist2, H2, W2, 0.0f, p2);

    // Scale 3
    down_kernel<3><<<dim3((W3 + 31) / 32, (H3 + 7) / 8, B), blk, 0, stream>>>(
        ref2, dist2, ref3, dist3, H2, W2, H3, W3, 0.0f);
    stats_kernel<3><<<dim3(ty3, tx3, B), blk, 0, stream>>>(ref3, dist3, H3, W3, 0.0f, p3);

    // Final: num/den per (b, scale)
    reduce_kernel<<<16, 256, 0, stream>>>(
        part, out,
        make_int4(0, B * n0, B * (n0 + n1), B * (n0 + n1 + n2)),
        make_int4(n0, n1, n2, n3));
}